// Round 5
// baseline (2668.824 us; speedup 1.0000x reference)
//
#include <hip/hip_runtime.h>
#include <math.h>

#define D_MODEL 1024
#define N_LAYERS 4
#define N_HEADS 16
#define HEAD_DIM 64
#define FF_DIM 4096
#define INNER 1024
#define QKV3 3072
#define EPS 1e-5f
#define ATT_SCALE 0.125f

typedef unsigned short u16;
typedef __attribute__((ext_vector_type(8))) short bf16x8;
typedef __attribute__((ext_vector_type(4))) float f32x4;

typedef const void __attribute__((address_space(1)))* gas1_t;
typedef void __attribute__((address_space(3)))* las3_t;

// async 16B/lane global->LDS (dest = wave-uniform base + lane*16)
__device__ __forceinline__ void gl_lds16(const void* g, void* l) {
    __builtin_amdgcn_global_load_lds((gas1_t)g, (las3_t)l, 16, 0, 0);
}
// same-wave LDS write->read ordering fence
__device__ __forceinline__ void lds_fence() {
    asm volatile("s_waitcnt lgkmcnt(0)" ::: "memory");
    __builtin_amdgcn_sched_barrier(0);
}

// ---- bf16 split helpers (RNE) ---------------------------------------------
__device__ __forceinline__ u16 bf_of(float x) {
    unsigned u = __float_as_uint(x);
    unsigned r = (u + 0x7fffu + ((u >> 16) & 1u)) >> 16;
    return (u16)r;
}
__device__ __forceinline__ float f_of_bf(u16 b) {
    return __uint_as_float(((unsigned)b) << 16);
}
__device__ __forceinline__ void split2(float x, u16& h, u16& l) {
    h = bf_of(x);
    l = bf_of(x - f_of_bf(h));
}

// ---------------------------------------------------------------------------
// LayerNorm. SPLIT -> hi/lo bf16 out, else fp32. 256 thr / row of 1024.
// ---------------------------------------------------------------------------
template<bool SPLIT>
__global__ __launch_bounds__(256) void ln_kernel(const float* __restrict__ in,
                                                 const float* __restrict__ sc,
                                                 const float* __restrict__ bs,
                                                 float* outf, u16* outh, u16* outl)
{
    int row = blockIdx.x;
    int t = threadIdx.x;
    const float4* x4 = (const float4*)(in + (size_t)row * D_MODEL);
    float4 v = x4[t];
    float sum = v.x + v.y + v.z + v.w;
    float sq  = v.x*v.x + v.y*v.y + v.z*v.z + v.w*v.w;
#pragma unroll
    for (int o = 32; o > 0; o >>= 1) {
        sum += __shfl_xor(sum, o);
        sq  += __shfl_xor(sq, o);
    }
    __shared__ float s1[4], s2[4];
    int w = t >> 6;
    if ((t & 63) == 0) { s1[w] = sum; s2[w] = sq; }
    __syncthreads();
    sum = s1[0] + s1[1] + s1[2] + s1[3];
    sq  = s2[0] + s2[1] + s2[2] + s2[3];
    float mu  = sum * (1.0f / D_MODEL);
    float var = sq * (1.0f / D_MODEL) - mu * mu;
    float rs  = rsqrtf(var + EPS);
    float4 s = ((const float4*)sc)[t];
    float4 b = ((const float4*)bs)[t];
    float o0 = (v.x - mu) * rs * s.x + b.x;
    float o1 = (v.y - mu) * rs * s.y + b.y;
    float o2 = (v.z - mu) * rs * s.z + b.z;
    float o3 = (v.w - mu) * rs * s.w + b.w;
    if (SPLIT) {
        u16 h0,l0,h1,l1,h2,l2,h3,l3;
        split2(o0,h0,l0); split2(o1,h1,l1); split2(o2,h2,l2); split2(o3,h3,l3);
        size_t idx = (size_t)row * D_MODEL + t * 4;
        *(ushort4*)&outh[idx] = make_ushort4(h0,h1,h2,h3);
        *(ushort4*)&outl[idx] = make_ushort4(l0,l1,l2,l3);
    } else {
        ((float4*)(outf + (size_t)row * D_MODEL))[t] = make_float4(o0,o1,o2,o3);
    }
}

// ---------------------------------------------------------------------------
// Weight transpose + split: W[K][N] fp32 -> Th/Tl[N][K] bf16. 32x32 tiles.
// ---------------------------------------------------------------------------
__global__ __launch_bounds__(256) void wsplit_kernel(const float* __restrict__ W,
                                                     u16* __restrict__ Th,
                                                     u16* __restrict__ Tl,
                                                     int K, int N)
{
    __shared__ float t[32][33];
    int tx = threadIdx.x & 31, ty = threadIdx.x >> 5;
    int n0 = blockIdx.x * 32, k0 = blockIdx.y * 32;
#pragma unroll
    for (int i = 0; i < 4; i++) {
        int r = ty + i * 8;
        t[r][tx] = W[(size_t)(k0 + r) * N + n0 + tx];
    }
    __syncthreads();
#pragma unroll
    for (int i = 0; i < 4; i++) {
        int r = ty + i * 8;
        float v = t[tx][r];
        u16 h, l; split2(v, h, l);
        size_t idx = (size_t)(n0 + r) * K + k0 + tx;
        Th[idx] = h; Tl[idx] = l;
    }
}

// ---------------------------------------------------------------------------
// V-transpose prep: v-part of split qkv [b][n][3072] -> vt[bh][d][n] (u16 move)
// block = (ntile 64, bh); thread (d = tid&63, seg = tid>>6) moves 16 n per half
// ---------------------------------------------------------------------------
__global__ __launch_bounds__(256) void vtprep(const u16* __restrict__ qh,
                                              const u16* __restrict__ ql,
                                              u16* __restrict__ vth,
                                              u16* __restrict__ vtl, int n)
{
    int bh = blockIdx.y;
    int b = bh >> 4, h = bh & 15;
    int nb = blockIdx.x * 64 + (threadIdx.x >> 6) * 16;
    int d = threadIdx.x & 63;
    const u16* srcH = qh + (size_t)(b * n + nb) * QKV3 + 2 * INNER + h * HEAD_DIM + d;
    const u16* srcL = ql + (size_t)(b * n + nb) * QKV3 + 2 * INNER + h * HEAD_DIM + d;
    u16 bh_[16], bl_[16];
#pragma unroll
    for (int i = 0; i < 16; i++) {
        bh_[i] = srcH[(size_t)i * QKV3];
        bl_[i] = srcL[(size_t)i * QKV3];
    }
    size_t drow = ((size_t)bh * HEAD_DIM + d) * n + nb;
    *(uint4*)&vth[drow]     = *(uint4*)&bh_[0];
    *(uint4*)&vth[drow + 8] = *(uint4*)&bh_[8];
    *(uint4*)&vtl[drow]     = *(uint4*)&bl_[0];
    *(uint4*)&vtl[drow + 8] = *(uint4*)&bl_[8];
}

// ---------------------------------------------------------------------------
// Split-bf16 MFMA GEMM. C = A@B (+bias/gelu/res), via AhBh + AhBl + AlBh.
// A: Ah/Al [M][K]; B pre-transposed: Bh/Bl [N][K]. 128x128 tile, BK=32,
// 4 waves 2x2 of 64x64. global_load_lds staging, hi/lo interleaved
// XOR-swizzled LDS tile [128 rows][8 x 16B chunks]:
//   chunk (r, cc) holds global (r, q), q = cc ^ (r&7); q -> half q>>2, part q&3
//   read (R,h,P) at byte R*128 + ((h*4+P)^(R&7))*16   (bank-balanced)
// ---------------------------------------------------------------------------
#define MFMA_BF16 __builtin_amdgcn_mfma_f32_16x16x32_bf16

template<bool BIAS, bool RES, bool GELU_, bool SPLITOUT>
__global__ __launch_bounds__(256, 2) void mfma_gemm(
    const u16* __restrict__ Ah, const u16* __restrict__ Al,
    const u16* __restrict__ Bh, const u16* __restrict__ Bl,
    const float* __restrict__ bias, const float* res,
    float* Cf, u16* Ch, u16* Cl,
    int M, int N, int K)
{
    __shared__ u16 Asm[128 * 64];   // 16KB
    __shared__ u16 Bsm[128 * 64];
    const int tid = threadIdx.x;
    const int bm0 = blockIdx.y * 128, bn0 = blockIdx.x * 128;
    const int wave = tid >> 6, lane = tid & 63;
    const int wm0 = (wave >> 1) * 64, wn0 = (wave & 1) * 64;
    const int fr = lane & 15, fp = lane >> 4;

    const u16* srcA[4]; const u16* srcB[4];
    u16* dstA[4]; u16* dstB[4];
#pragma unroll
    for (int s = 0; s < 4; s++) {
        int t_ = wave * 4 + s;
        int c  = t_ * 64 + lane;
        int r  = c >> 3;
        int q  = (c & 7) ^ (r & 7);
        const u16* Asel = (q & 4) ? Al : Ah;
        const u16* Bsel = (q & 4) ? Bl : Bh;
        srcA[s] = Asel + (size_t)(bm0 + r) * K + (q & 3) * 8;
        srcB[s] = Bsel + (size_t)(bn0 + r) * K + (q & 3) * 8;
        dstA[s] = &Asm[t_ * 512];
        dstB[s] = &Bsm[t_ * 512];
    }

    const bf16x8 *pAh[4], *pAl[4], *pBh[4], *pBl[4];
#pragma unroll
    for (int i = 0; i < 4; i++) {
        int Ra = wm0 + i * 16 + fr, Rb = wn0 + i * 16 + fr;
        int s7 = fr & 7;
        pAh[i] = (const bf16x8*)&Asm[(Ra * 8 + (fp ^ s7)) * 8];
        pAl[i] = (const bf16x8*)&Asm[(Ra * 8 + ((fp + 4) ^ s7)) * 8];
        pBh[i] = (const bf16x8*)&Bsm[(Rb * 8 + (fp ^ s7)) * 8];
        pBl[i] = (const bf16x8*)&Bsm[(Rb * 8 + ((fp + 4) ^ s7)) * 8];
    }

    f32x4 acc[4][4];
#pragma unroll
    for (int i = 0; i < 4; i++)
#pragma unroll
        for (int j = 0; j < 4; j++)
#pragma unroll
            for (int q = 0; q < 4; q++) acc[i][j][q] = 0.0f;

    for (int k0 = 0; k0 < K; k0 += 32) {
        __syncthreads();
#pragma unroll
        for (int s = 0; s < 4; s++) {
            gl_lds16(srcA[s] + k0, dstA[s]);
            gl_lds16(srcB[s] + k0, dstB[s]);
        }
        __syncthreads();

        bf16x8 fah[4], fal[4], fbh[4], fbl[4];
#pragma unroll
        for (int i = 0; i < 4; i++) {
            fah[i] = *pAh[i]; fal[i] = *pAl[i];
            fbh[i] = *pBh[i]; fbl[i] = *pBl[i];
        }
#pragma unroll
        for (int i = 0; i < 4; i++)
#pragma unroll
            for (int j = 0; j < 4; j++) {
                acc[i][j] = MFMA_BF16(fah[i], fbh[j], acc[i][j], 0, 0, 0);
                acc[i][j] = MFMA_BF16(fah[i], fbl[j], acc[i][j], 0, 0, 0);
                acc[i][j] = MFMA_BF16(fal[i], fbh[j], acc[i][j], 0, 0, 0);
            }
    }

#pragma unroll
    for (int i = 0; i < 4; i++)
#pragma unroll
        for (int j = 0; j < 4; j++) {
            int col = bn0 + wn0 + j * 16 + fr;
            float bv = BIAS ? bias[col] : 0.0f;
#pragma unroll
            for (int q = 0; q < 4; q++) {
                int row = bm0 + wm0 + i * 16 + fp * 4 + q;
                float t = acc[i][j][q] + bv;
                if (GELU_) t = 0.5f * t * (1.0f + erff(t * 0.70710678118654752f));
                if (RES) t += res[(size_t)row * N + col];
                size_t idx = (size_t)row * N + col;
                if (SPLITOUT) { u16 h, l; split2(t, h, l); Ch[idx] = h; Cl[idx] = l; }
                else Cf[idx] = t;
            }
        }
}

// ---------------------------------------------------------------------------
// Split-bf16 MFMA flash attention.
// Block: 256 thr = 4 waves; wave owns 16 q-rows; QB=64 q-rows/block; JB=64.
// S^T = mfma(K, Q): lane holds q = lane&15, j = jt*16 + (lane>>4)*4 + reg.
// Softmax per lane (16 j-vals of one q) + shfl_xor(16,32) cross-copies.
// P split hi/lo -> per-wave swizzled LDS [q][j] -> B-frag of
// OUT^T = mfma(V^T, P^T). K and V^T staged via pre-swizzled global_load_lds.
// Grid: 1D (nbh*qblocks), XCD-grouped so one bh's K/V^T stays in one L2.
// ---------------------------------------------------------------------------
__global__ __launch_bounds__(256, 2) void attn_mfma(
    const u16* __restrict__ qh, const u16* __restrict__ ql,
    const u16* __restrict__ vth, const u16* __restrict__ vtl,
    u16* __restrict__ oh, u16* __restrict__ ol, int n, int qblocks)
{
    __shared__ u16 Kt[2][64 * 64];     // [half][j-row][8 slots] swizzled, 8KB ea
    __shared__ u16 Vt[2][64 * 64];     // [half][d-row][8 slots] swizzled
    __shared__ u16 Pb[4][2][16 * 64];  // [wave][half][q][j] swizzled, 2KB ea

    // XCD-grouped remap (grid % 8 == 0)
    int total = gridDim.x;
    int per_xcd = total >> 3;
    int g = blockIdx.x;
    int flat = (g & 7) * per_xcd + (g >> 3);
    int bh = flat / qblocks;
    int qb = flat - bh * qblocks;
    int b = bh >> 4, h = bh & 15;
    int q0 = qb * 64;

    const int tid = threadIdx.x;
    const int wave = tid >> 6, lane = tid & 63;
    const int q_ = lane & 15, qx = q_ & 7;

    // Q fragments in registers (B-operand: col q = lane&15, 8 contig d)
    bf16x8 qfh[2], qfl[2];
    {
        size_t qo = (size_t)(b * n + q0 + wave * 16 + q_) * QKV3
                  + h * HEAD_DIM + (lane >> 4) * 8;
        qfh[0] = *(const bf16x8*)&qh[qo];
        qfh[1] = *(const bf16x8*)&qh[qo + 32];
        qfl[0] = *(const bf16x8*)&ql[qo];
        qfl[1] = *(const bf16x8*)&ql[qo + 32];
    }

    f32x4 oa[4];
#pragma unroll
    for (int dt = 0; dt < 4; dt++)
#pragma unroll
        for (int r = 0; r < 4; r++) oa[dt][r] = 0.0f;
    float mreg = -1e30f, lreg = 0.0f;

    for (int j0 = 0; j0 < n; j0 += 64) {
        __syncthreads();   // prior tile's LDS reads complete
        // stage K (issues 0..15) and V^T (16..31); 8 issues per wave
#pragma unroll
        for (int e = 0; e < 8; e++) {
            int ei = wave * 8 + e;
            int half = (ei >> 3) & 1;
            int cb = ei & 7;
            int c = cb * 64 + lane;
            int r = c >> 3;
            int p = (c & 7) ^ (r & 7);   // pre-swizzled source slot
            if (ei < 16) {
                const u16* src = (half ? ql : qh)
                    + (size_t)(b * n + j0 + r) * QKV3 + INNER + h * HEAD_DIM + p * 8;
                gl_lds16(src, &Kt[half][cb * 512]);
            } else {
                const u16* src = (half ? vtl : vth)
                    + ((size_t)bh * HEAD_DIM + r) * n + j0 + p * 8;
                gl_lds16(src, &Vt[half][cb * 512]);
            }
        }
        __syncthreads();   // drains vmcnt: K/V^T ready

        // ---- S^T = (Kh+Kl)(Qh+Ql), 3 products ----
        f32x4 sa[4];
#pragma unroll
        for (int jt = 0; jt < 4; jt++) {
#pragma unroll
            for (int r = 0; r < 4; r++) sa[jt][r] = 0.0f;
            int jr = jt * 16 + q_;
            int ro = jr * 64, x7 = jr & 7;
#pragma unroll
            for (int ks = 0; ks < 2; ks++) {
                int sl = (ks * 4 + (lane >> 4)) ^ x7;
                bf16x8 kh_ = *(const bf16x8*)&Kt[0][ro + sl * 8];
                bf16x8 kl_ = *(const bf16x8*)&Kt[1][ro + sl * 8];
                sa[jt] = MFMA_BF16(kh_, qfh[ks], sa[jt], 0, 0, 0);
                sa[jt] = MFMA_BF16(kh_, qfl[ks], sa[jt], 0, 0, 0);
                sa[jt] = MFMA_BF16(kl_, qfh[ks], sa[jt], 0, 0, 0);
            }
        }

        // ---- online softmax (lane's q = lane&15; 16 j-values in-lane) ----
        float p[16];
        float mt = -1e30f;
#pragma unroll
        for (int jt = 0; jt < 4; jt++)
#pragma unroll
            for (int r = 0; r < 4; r++) {
                float sv = sa[jt][r] * ATT_SCALE;
                p[jt * 4 + r] = sv;
                mt = fmaxf(mt, sv);
            }
        mt = fmaxf(mt, __shfl_xor(mt, 16));
        mt = fmaxf(mt, __shfl_xor(mt, 32));
        float mn = fmaxf(mreg, mt);
        float al = __expf(mreg - mn);
        float ps = 0.0f;
#pragma unroll
        for (int t = 0; t < 16; t++) { p[t] = __expf(p[t] - mn); ps += p[t]; }
        ps += __shfl_xor(ps, 16);
        ps += __shfl_xor(ps, 32);
        lreg = lreg * al + ps;
        mreg = mn;
#pragma unroll
        for (int dt = 0; dt < 4; dt++)
#pragma unroll
            for (int r = 0; r < 4; r++) oa[dt][r] *= al;

        // ---- P split -> per-wave LDS [q][j] (swizzled) ----
#pragma unroll
        for (int jt = 0; jt < 4; jt++) {
            int jb = jt * 16 + (lane >> 4) * 4;
            int uo = q_ * 64 + (((jb >> 3) ^ qx) * 8) + (jb & 7);
            ushort4 wh, wl;
            split2(p[jt * 4 + 0], wh.x, wl.x);
            split2(p[jt * 4 + 1], wh.y, wl.y);
            split2(p[jt * 4 + 2], wh.z, wl.z);
            split2(p[jt * 4 + 3], wh.w, wl.w);
            *(ushort4*)&Pb[wave][0][uo] = wh;
            *(ushort4*)&Pb[wave][1][uo] = wl;
        }
        lds_fence();

        // ---- OUT^T += (Vh+Vl)(Ph+Pl), 3 products ----
#pragma unroll
        for (int dt = 0; dt < 4; dt++) {
            int dr = dt * 16 + q_;
            int rv = dr * 64, d7 = dr & 7;
#pragma unroll
            for (int js = 0; js < 2; js++) {
                int sl = js * 4 + (lane >> 4);
                bf16x8 vh_ = *(const bf16x8*)&Vt[0][rv + ((sl ^ d7) * 8)];
                bf16x8 vl_ = *(const bf16x8*)&Vt[1][rv + ((sl ^ d7) * 8)];
                int po = q_ * 64 + ((sl ^ qx) * 8);
                bf16x8 ph_ = *(const bf16x8*)&Pb[wave][0][po];
                bf16x8 pl_ = *(const bf16x8*)&Pb[wave][1][po];
                oa[dt] = MFMA_BF16(vh_, ph_, oa[dt], 0, 0, 0);
                oa[dt] = MFMA_BF16(vh_, pl_, oa[dt], 0, 0, 0);
                oa[dt] = MFMA_BF16(vl_, ph_, oa[dt], 0, 0, 0);
            }
        }
    }

    // ---- finalize: /l, split, bounce via Pb for coalesced 16B stores ----
    float inv = 1.0f / lreg;
#pragma unroll
    for (int dt = 0; dt < 4; dt++) {
        int db = dt * 16 + (lane >> 4) * 4;
        int uo = q_ * 64 + (((db >> 3) ^ qx) * 8) + (db & 7);
        ushort4 wh, wl;
        split2(oa[dt][0] * inv, wh.x, wl.x);
        split2(oa[dt][1] * inv, wh.y, wl.y);
        split2(oa[dt][2] * inv, wh.z, wl.z);
        split2(oa[dt][3] * inv, wh.w, wl.w);
        *(ushort4*)&Pb[wave][0][uo] = wh;
        *(ushort4*)&Pb[wave][1][uo] = wl;
    }
    lds_fence();
#pragma unroll
    for (int pass = 0; pass < 2; pass++) {
        int qq = lane >> 2;
        int sl = (lane & 3) + pass * 4;
        int uo = qq * 64 + ((sl ^ (qq & 7)) * 8);
        bf16x8 vh_ = *(const bf16x8*)&Pb[wave][0][uo];
        bf16x8 vl_ = *(const bf16x8*)&Pb[wave][1][uo];
        size_t orow = (size_t)(b * n + q0 + wave * 16 + qq) * INNER
                    + h * HEAD_DIM + sl * 8;
        *(bf16x8*)&oh[orow] = vh_;
        *(bf16x8*)&ol[orow] = vl_;
    }
}

// ---------------------------------------------------------------------------
// Host launch
// ---------------------------------------------------------------------------
extern "C" void kernel_launch(void* const* d_in, const int* in_sizes, int n_in,
                              void* d_out, int out_size, void* d_ws, size_t ws_size,
                              hipStream_t stream)
{
    const float* x_in   = (const float*)d_in[0];
    const float* Wqkv   = (const float*)d_in[1];
    const float* Wout   = (const float*)d_in[2];
    const float* ln1_s  = (const float*)d_in[3];
    const float* ln1_b  = (const float*)d_in[4];
    const float* W1     = (const float*)d_in[5];
    const float* b1     = (const float*)d_in[6];
    const float* W2     = (const float*)d_in[7];
    const float* b2     = (const float*)d_in[8];
    const float* ln2_s  = (const float*)d_in[9];
    const float* ln2_b  = (const float*)d_in[10];
    const float* lnf_s  = (const float*)d_in[11];
    const float* lnf_b  = (const float*)d_in[12];
    float* outp = (float*)d_out;

    int rows = in_sizes[0] / D_MODEL;   // 4096
    int n = 2048;
    int batch = rows / n;               // 2
    int nbh = batch * N_HEADS;          // 32
    int qblocks = n / 64;               // 32

    // ---- workspace (~134 MB) ----
    char* p = (char*)d_ws;
    float* x = (float*)p;  p += (size_t)rows * D_MODEL * 4;       // 16.8 MB
    u16* hh  = (u16*)p;    p += (size_t)rows * D_MODEL * 2;       //  8.4
    u16* hl  = (u16*)p;    p += (size_t)rows * D_MODEL * 2;       //  8.4
    // BIG union region: {qkvh,qkvl} (attention phase) / {ffh,ffl} (FF phase)
    u16* qkvh = (u16*)p;
    u16* ffh  = (u16*)p;   p += (size_t)rows * FF_DIM * 2;        // 33.6
    u16* qkvl = (u16*)p;
    u16* ffl  = (u16*)p;   p += (size_t)rows * FF_DIM * 2;        // 33.6
    u16* vth = (u16*)p;    p += (size_t)nbh * HEAD_DIM * n * 2;   //  8.4
    u16* vtl = (u16*)p;    p += (size_t)nbh * HEAD_DIM * n * 2;   //  8.4
    u16* wbh = (u16*)p;    p += (size_t)FF_DIM * D_MODEL * 2;     //  8.4
    u16* wbl = (u16*)p;    p += (size_t)FF_DIM * D_MODEL * 2;     //  8.4

    hipMemcpyAsync(x, x_in, (size_t)rows * D_MODEL * 4, hipMemcpyDeviceToDevice, stream);

    dim3 blk(256);
    for (int i = 0; i < N_LAYERS; i++) {
        const float* Wqkv_i = Wqkv + (size_t)i * D_MODEL * QKV3;
        const float* Wout_i = Wout + (size_t)i * INNER * D_MODEL;
        const float* W1_i   = W1 + (size_t)i * D_MODEL * FF_DIM;
        const float* W2_i   = W2 + (size_t)i * FF_DIM * D_MODEL;

        // -- attention block --
        wsplit_kernel<<<dim3(QKV3/32, D_MODEL/32), blk, 0, stream>>>(Wqkv_i, wbh, wbl, D_MODEL, QKV3);
        ln_kernel<true><<<rows, blk, 0, stream>>>(x, ln1_s + i*D_MODEL, ln1_b + i*D_MODEL,
                                                  nullptr, hh, hl);
        mfma_gemm<false,false,false,true><<<dim3(QKV3/128, rows/128), blk, 0, stream>>>(
            hh, hl, wbh, wbl, nullptr, nullptr, nullptr, qkvh, qkvl, rows, QKV3, D_MODEL);
        vtprep<<<dim3(n/64, nbh), blk, 0, stream>>>(qkvh, qkvl, vth, vtl, n);
        attn_mfma<<<nbh * qblocks, blk, 0, stream>>>(qkvh, qkvl, vth, vtl, hh, hl, n, qblocks);
        wsplit_kernel<<<dim3(D_MODEL/32, INNER/32), blk, 0, stream>>>(Wout_i, wbh, wbl, INNER, D_MODEL);
        mfma_gemm<false,true,false,false><<<dim3(D_MODEL/128, rows/128), blk, 0, stream>>>(
            hh, hl, wbh, wbl, nullptr, x, x, nullptr, nullptr, rows, D_MODEL, INNER);

        // -- feedforward block --
        ln_kernel<true><<<rows, blk, 0, stream>>>(x, ln2_s + i*D_MODEL, ln2_b + i*D_MODEL,
                                                  nullptr, hh, hl);
        wsplit_kernel<<<dim3(FF_DIM/32, D_MODEL/32), blk, 0, stream>>>(W1_i, wbh, wbl, D_MODEL, FF_DIM);
        mfma_gemm<true,false,true,true><<<dim3(FF_DIM/128, rows/128), blk, 0, stream>>>(
            hh, hl, wbh, wbl, b1 + (size_t)i*FF_DIM, nullptr, nullptr, ffh, ffl,
            rows, FF_DIM, D_MODEL);
        wsplit_kernel<<<dim3(D_MODEL/32, FF_DIM/32), blk, 0, stream>>>(W2_i, wbh, wbl, FF_DIM, D_MODEL);
        mfma_gemm<true,true,false,false><<<dim3(D_MODEL/128, rows/128), blk, 0, stream>>>(
            ffh, ffl, wbh, wbl, b2 + (size_t)i*D_MODEL, x, x, nullptr, nullptr,
            rows, D_MODEL, FF_DIM);
    }
    ln_kernel<false><<<rows, blk, 0, stream>>>(x, lnf_s, lnf_b, outp, nullptr, nullptr);
}

// Round 7
// 2653.585 us; speedup vs baseline: 1.0057x; 1.0057x over previous
//
#include <hip/hip_runtime.h>
#include <math.h>

#define D_MODEL 1024
#define N_LAYERS 4
#define N_HEADS 16
#define HEAD_DIM 64
#define FF_DIM 4096
#define INNER 1024
#define QKV3 3072
#define EPS 1e-5f
#define ATT_SCALE 0.125f

typedef unsigned short u16;
typedef __attribute__((ext_vector_type(8))) short bf16x8;
typedef __attribute__((ext_vector_type(4))) float f32x4;

typedef const void __attribute__((address_space(1)))* gas1_t;
typedef void __attribute__((address_space(3)))* las3_t;

// async 16B/lane global->LDS (dest = wave-uniform base + lane*16)
__device__ __forceinline__ void gl_lds16(const void* g, void* l) {
    __builtin_amdgcn_global_load_lds((gas1_t)g, (las3_t)l, 16, 0, 0);
}
// same-wave LDS write->read ordering fence
__device__ __forceinline__ void lds_fence() {
    asm volatile("s_waitcnt lgkmcnt(0)" ::: "memory");
    __builtin_amdgcn_sched_barrier(0);
}

// ---- bf16 split helpers (RNE) ---------------------------------------------
__device__ __forceinline__ u16 bf_of(float x) {
    unsigned u = __float_as_uint(x);
    unsigned r = (u + 0x7fffu + ((u >> 16) & 1u)) >> 16;
    return (u16)r;
}
__device__ __forceinline__ float f_of_bf(u16 b) {
    return __uint_as_float(((unsigned)b) << 16);
}
__device__ __forceinline__ void split2(float x, u16& h, u16& l) {
    h = bf_of(x);
    l = bf_of(x - f_of_bf(h));
}

// ---------------------------------------------------------------------------
// LayerNorm. SPLIT -> hi/lo bf16 out, else fp32. 256 thr / row of 1024.
// ---------------------------------------------------------------------------
template<bool SPLIT>
__global__ __launch_bounds__(256) void ln_kernel(const float* __restrict__ in,
                                                 const float* __restrict__ sc,
                                                 const float* __restrict__ bs,
                                                 float* outf, u16* outh, u16* outl)
{
    int row = blockIdx.x;
    int t = threadIdx.x;
    const float4* x4 = (const float4*)(in + (size_t)row * D_MODEL);
    float4 v = x4[t];
    float sum = v.x + v.y + v.z + v.w;
    float sq  = v.x*v.x + v.y*v.y + v.z*v.z + v.w*v.w;
#pragma unroll
    for (int o = 32; o > 0; o >>= 1) {
        sum += __shfl_xor(sum, o);
        sq  += __shfl_xor(sq, o);
    }
    __shared__ float s1[4], s2[4];
    int w = t >> 6;
    if ((t & 63) == 0) { s1[w] = sum; s2[w] = sq; }
    __syncthreads();
    sum = s1[0] + s1[1] + s1[2] + s1[3];
    sq  = s2[0] + s2[1] + s2[2] + s2[3];
    float mu  = sum * (1.0f / D_MODEL);
    float var = sq * (1.0f / D_MODEL) - mu * mu;
    float rs  = rsqrtf(var + EPS);
    float4 s = ((const float4*)sc)[t];
    float4 b = ((const float4*)bs)[t];
    float o0 = (v.x - mu) * rs * s.x + b.x;
    float o1 = (v.y - mu) * rs * s.y + b.y;
    float o2 = (v.z - mu) * rs * s.z + b.z;
    float o3 = (v.w - mu) * rs * s.w + b.w;
    if (SPLIT) {
        u16 h0,l0,h1,l1,h2,l2,h3,l3;
        split2(o0,h0,l0); split2(o1,h1,l1); split2(o2,h2,l2); split2(o3,h3,l3);
        size_t idx = (size_t)row * D_MODEL + t * 4;
        *(ushort4*)&outh[idx] = make_ushort4(h0,h1,h2,h3);
        *(ushort4*)&outl[idx] = make_ushort4(l0,l1,l2,l3);
    } else {
        ((float4*)(outf + (size_t)row * D_MODEL))[t] = make_float4(o0,o1,o2,o3);
    }
}

// ---------------------------------------------------------------------------
// Weight transpose + split: W[K][N] fp32 -> Th/Tl[N][K] bf16. 32x32 tiles.
// ---------------------------------------------------------------------------
__global__ __launch_bounds__(256) void wsplit_kernel(const float* __restrict__ W,
                                                     u16* __restrict__ Th,
                                                     u16* __restrict__ Tl,
                                                     int K, int N)
{
    __shared__ float t[32][33];
    int tx = threadIdx.x & 31, ty = threadIdx.x >> 5;
    int n0 = blockIdx.x * 32, k0 = blockIdx.y * 32;
#pragma unroll
    for (int i = 0; i < 4; i++) {
        int r = ty + i * 8;
        t[r][tx] = W[(size_t)(k0 + r) * N + n0 + tx];
    }
    __syncthreads();
#pragma unroll
    for (int i = 0; i < 4; i++) {
        int r = ty + i * 8;
        float v = t[tx][r];
        u16 h, l; split2(v, h, l);
        size_t idx = (size_t)(n0 + r) * K + k0 + tx;
        Th[idx] = h; Tl[idx] = l;
    }
}

// ---------------------------------------------------------------------------
// V-transpose prep: v-part of split qkv [b][n][3072] -> vt[bh][d][n]
// ---------------------------------------------------------------------------
__global__ __launch_bounds__(256) void vtprep(const u16* __restrict__ qh,
                                              const u16* __restrict__ ql,
                                              u16* __restrict__ vth,
                                              u16* __restrict__ vtl, int n)
{
    int bh = blockIdx.y;
    int b = bh >> 4, h = bh & 15;
    int nb = blockIdx.x * 64 + (threadIdx.x >> 6) * 16;
    int d = threadIdx.x & 63;
    const u16* srcH = qh + (size_t)(b * n + nb) * QKV3 + 2 * INNER + h * HEAD_DIM + d;
    const u16* srcL = ql + (size_t)(b * n + nb) * QKV3 + 2 * INNER + h * HEAD_DIM + d;
    u16 bh_[16], bl_[16];
#pragma unroll
    for (int i = 0; i < 16; i++) {
        bh_[i] = srcH[(size_t)i * QKV3];
        bl_[i] = srcL[(size_t)i * QKV3];
    }
    size_t drow = ((size_t)bh * HEAD_DIM + d) * n + nb;
    *(uint4*)&vth[drow]     = *(uint4*)&bh_[0];
    *(uint4*)&vth[drow + 8] = *(uint4*)&bh_[8];
    *(uint4*)&vtl[drow]     = *(uint4*)&bl_[0];
    *(uint4*)&vtl[drow + 8] = *(uint4*)&bl_[8];
}

// ---------------------------------------------------------------------------
// Split-bf16 MFMA GEMM. C = A@B (+bias/gelu/res), via AhBh + AhBl + AlBh.
// A: Ah/Al [M][K]; B pre-transposed: Bh/Bl [N][K]. 128x128 tile, BK=32,
// 4 waves 2x2 of 64x64.
// (a) 2-phase double-buffered staging — issue next K-step's global_load_lds
// BEFORE computing current, one vmcnt(0)+barrier per step (T3-minimum);
// (b) 1D grid, bijective XCD-chunk decode + gm-grouped column-major raster
// so panel-sharing blocks co-reside on one XCD's L2.
// LDS swizzle (validated r5): chunk (r,cc) holds (r, q=cc^(r&7)),
// read (R,h,P) at byte R*128 + ((h*4+P)^(R&7))*16.
// ---------------------------------------------------------------------------
#define MFMA_BF16 __builtin_amdgcn_mfma_f32_16x16x32_bf16

template<bool BIAS, bool RES, bool GELU_, bool SPLITOUT>
__global__ __launch_bounds__(256, 2) void mfma_gemm(
    const u16* __restrict__ Ah, const u16* __restrict__ Al,
    const u16* __restrict__ Bh, const u16* __restrict__ Bl,
    const float* __restrict__ bias, const float* res,
    float* Cf, u16* Ch, u16* Cl,
    int M, int N, int K, int gm)
{
    __shared__ u16 Asm[2][128 * 64];   // 2 x 16KB double buffer
    __shared__ u16 Bsm[2][128 * 64];

    // ---- XCD-chunked grouped raster decode ----
    int nwg = gridDim.x;               // (M/128)*(N/128), % 8 == 0
    int qq = nwg >> 3;
    int wg = (blockIdx.x & 7) * qq + (blockIdx.x >> 3);
    int ntn = N >> 7;
    int pg = gm * ntn;
    int grp = wg / pg, rem = wg - grp * pg;
    int mt = grp * gm + (rem % gm);
    int nt = rem / gm;
    const int bm0 = mt << 7, bn0 = nt << 7;

    const int tid = threadIdx.x;
    const int wave = tid >> 6, lane = tid & 63;
    const int wm0 = (wave >> 1) * 64, wn0 = (wave & 1) * 64;
    const int fr = lane & 15, fp = lane >> 4;

    // staging descriptors: per wave 4 A-issues + 4 B-issues (1KB each)
    const u16* srcA[4]; const u16* srcB[4];
    u16* dstA[4]; u16* dstB[4];
#pragma unroll
    for (int s = 0; s < 4; s++) {
        int t_ = wave * 4 + s;
        int c  = t_ * 64 + lane;
        int r  = c >> 3;
        int q  = (c & 7) ^ (r & 7);
        const u16* Asel = (q & 4) ? Al : Ah;
        const u16* Bsel = (q & 4) ? Bl : Bh;
        srcA[s] = Asel + (size_t)(bm0 + r) * K + (q & 3) * 8;
        srcB[s] = Bsel + (size_t)(bn0 + r) * K + (q & 3) * 8;
        dstA[s] = &Asm[0][t_ * 512];
        dstB[s] = &Bsm[0][t_ * 512];
    }

    // fragment read offsets (u16 elements within one buffer)
    int oAh[4], oAl[4], oBh[4], oBl[4];
#pragma unroll
    for (int i = 0; i < 4; i++) {
        int Ra = wm0 + i * 16 + fr, Rb = wn0 + i * 16 + fr;
        int s7 = fr & 7;
        oAh[i] = (Ra * 8 + (fp ^ s7)) * 8;
        oAl[i] = (Ra * 8 + ((fp + 4) ^ s7)) * 8;
        oBh[i] = (Rb * 8 + (fp ^ s7)) * 8;
        oBl[i] = (Rb * 8 + ((fp + 4) ^ s7)) * 8;
    }

    f32x4 acc[4][4];
#pragma unroll
    for (int i = 0; i < 4; i++)
#pragma unroll
        for (int j = 0; j < 4; j++)
#pragma unroll
            for (int q = 0; q < 4; q++) acc[i][j][q] = 0.0f;

#define STAGE(B, K0) do { \
    _Pragma("unroll") \
    for (int s = 0; s < 4; s++) { \
        gl_lds16(srcA[s] + (K0), dstA[s] + (B) * 8192); \
        gl_lds16(srcB[s] + (K0), dstB[s] + (B) * 8192); \
    } } while (0)

#define COMPUTE(B) do { \
    bf16x8 fah[4], fal[4], fbh[4], fbl[4]; \
    _Pragma("unroll") \
    for (int i = 0; i < 4; i++) { \
        fah[i] = *(const bf16x8*)&Asm[B][oAh[i]]; \
        fal[i] = *(const bf16x8*)&Asm[B][oAl[i]]; \
        fbh[i] = *(const bf16x8*)&Bsm[B][oBh[i]]; \
        fbl[i] = *(const bf16x8*)&Bsm[B][oBl[i]]; \
    } \
    _Pragma("unroll") \
    for (int i = 0; i < 4; i++) \
    _Pragma("unroll") \
        for (int j = 0; j < 4; j++) { \
            acc[i][j] = MFMA_BF16(fah[i], fbh[j], acc[i][j], 0, 0, 0); \
            acc[i][j] = MFMA_BF16(fah[i], fbl[j], acc[i][j], 0, 0, 0); \
            acc[i][j] = MFMA_BF16(fal[i], fbh[j], acc[i][j], 0, 0, 0); \
        } } while (0)

    // ---- 2-phase pipelined K-loop ----
    STAGE(0, 0);
    __syncthreads();                   // drains vmcnt(0): buf0 ready
    int cur = 0;
    for (int k0 = 32; k0 < K; k0 += 32) {
        STAGE(cur ^ 1, k0);            // prefetch next (latency hidden below)
        COMPUTE(cur);
        __syncthreads();               // drains vmcnt(0): next buf ready
        cur ^= 1;
    }
    COMPUTE(cur);
#undef STAGE
#undef COMPUTE

    // epilogue
#pragma unroll
    for (int i = 0; i < 4; i++)
#pragma unroll
        for (int j = 0; j < 4; j++) {
            int col = bn0 + wn0 + j * 16 + fr;
            float bv = BIAS ? bias[col] : 0.0f;
#pragma unroll
            for (int q = 0; q < 4; q++) {
                int row = bm0 + wm0 + i * 16 + fp * 4 + q;
                float t = acc[i][j][q] + bv;
                if (GELU_) t = 0.5f * t * (1.0f + erff(t * 0.70710678118654752f));
                if (RES) t += res[(size_t)row * N + col];
                size_t idx = (size_t)row * N + col;
                if (SPLITOUT) { u16 h, l; split2(t, h, l); Ch[idx] = h; Cl[idx] = l; }
                else Cf[idx] = t;
            }
        }
}

// ---------------------------------------------------------------------------
// Split-bf16 MFMA flash attention (validated round-5 version, unchanged).
// ---------------------------------------------------------------------------
__global__ __launch_bounds__(256, 2) void attn_mfma(
    const u16* __restrict__ qh, const u16* __restrict__ ql,
    const u16* __restrict__ vth, const u16* __restrict__ vtl,
    u16* __restrict__ oh, u16* __restrict__ ol, int n, int qblocks)
{
    __shared__ u16 Kt[2][64 * 64];
    __shared__ u16 Vt[2][64 * 64];
    __shared__ u16 Pb[4][2][16 * 64];

    int total = gridDim.x;
    int per_xcd = total >> 3;
    int g = blockIdx.x;
    int flat = (g & 7) * per_xcd + (g >> 3);
    int bh = flat / qblocks;
    int qb = flat - bh * qblocks;
    int b = bh >> 4, h = bh & 15;
    int q0 = qb * 64;

    const int tid = threadIdx.x;
    const int wave = tid >> 6, lane = tid & 63;
    const int q_ = lane & 15, qx = q_ & 7;

    bf16x8 qfh[2], qfl[2];
    {
        size_t qo = (size_t)(b * n + q0 + wave * 16 + q_) * QKV3
                  + h * HEAD_DIM + (lane >> 4) * 8;
        qfh[0] = *(const bf16x8*)&qh[qo];
        qfh[1] = *(const bf16x8*)&qh[qo + 32];
        qfl[0] = *(const bf16x8*)&ql[qo];
        qfl[1] = *(const bf16x8*)&ql[qo + 32];
    }

    f32x4 oa[4];
#pragma unroll
    for (int dt = 0; dt < 4; dt++)
#pragma unroll
        for (int r = 0; r < 4; r++) oa[dt][r] = 0.0f;
    float mreg = -1e30f, lreg = 0.0f;

    for (int j0 = 0; j0 < n; j0 += 64) {
        __syncthreads();
#pragma unroll
        for (int e = 0; e < 8; e++) {
            int ei = wave * 8 + e;
            int half = (ei >> 3) & 1;
            int cb = ei & 7;
            int c = cb * 64 + lane;
            int r = c >> 3;
            int p = (c & 7) ^ (r & 7);
            if (ei < 16) {
                const u16* src = (half ? ql : qh)
                    + (size_t)(b * n + j0 + r) * QKV3 + INNER + h * HEAD_DIM + p * 8;
                gl_lds16(src, &Kt[half][cb * 512]);
            } else {
                const u16* src = (half ? vtl : vth)
                    + ((size_t)bh * HEAD_DIM + r) * n + j0 + p * 8;
                gl_lds16(src, &Vt[half][cb * 512]);
            }
        }
        __syncthreads();

        f32x4 sa[4];
#pragma unroll
        for (int jt = 0; jt < 4; jt++) {
#pragma unroll
            for (int r = 0; r < 4; r++) sa[jt][r] = 0.0f;
            int jr = jt * 16 + q_;
            int ro = jr * 64, x7 = jr & 7;
#pragma unroll
            for (int ks = 0; ks < 2; ks++) {
                int sl = (ks * 4 + (lane >> 4)) ^ x7;
                bf16x8 kh_ = *(const bf16x8*)&Kt[0][ro + sl * 8];
                bf16x8 kl_ = *(const bf16x8*)&Kt[1][ro + sl * 8];
                sa[jt] = MFMA_BF16(kh_, qfh[ks], sa[jt], 0, 0, 0);
                sa[jt] = MFMA_BF16(kh_, qfl[ks], sa[jt], 0, 0, 0);
                sa[jt] = MFMA_BF16(kl_, qfh[ks], sa[jt], 0, 0, 0);
            }
        }

        float p[16];
        float mt = -1e30f;
#pragma unroll
        for (int jt = 0; jt < 4; jt++)
#pragma unroll
            for (int r = 0; r < 4; r++) {
                float sv = sa[jt][r] * ATT_SCALE;
                p[jt * 4 + r] = sv;
                mt = fmaxf(mt, sv);
            }
        mt = fmaxf(mt, __shfl_xor(mt, 16));
        mt = fmaxf(mt, __shfl_xor(mt, 32));
        float mn = fmaxf(mreg, mt);
        float al = __expf(mreg - mn);
        float ps = 0.0f;
#pragma unroll
        for (int t = 0; t < 16; t++) { p[t] = __expf(p[t] - mn); ps += p[t]; }
        ps += __shfl_xor(ps, 16);
        ps += __shfl_xor(ps, 32);
        lreg = lreg * al + ps;
        mreg = mn;
#pragma unroll
        for (int dt = 0; dt < 4; dt++)
#pragma unroll
            for (int r = 0; r < 4; r++) oa[dt][r] *= al;

#pragma unroll
        for (int jt = 0; jt < 4; jt++) {
            int jb = jt * 16 + (lane >> 4) * 4;
            int uo = q_ * 64 + (((jb >> 3) ^ qx) * 8) + (jb & 7);
            ushort4 wh, wl;
            split2(p[jt * 4 + 0], wh.x, wl.x);
            split2(p[jt * 4 + 1], wh.y, wl.y);
            split2(p[jt * 4 + 2], wh.z, wl.z);
            split2(p[jt * 4 + 3], wh.w, wl.w);
            *(ushort4*)&Pb[wave][0][uo] = wh;
            *(ushort4*)&Pb[wave][1][uo] = wl;
        }
        lds_fence();

#pragma unroll
        for (int dt = 0; dt < 4; dt++) {
            int dr = dt * 16 + q_;
            int rv = dr * 64, d7 = dr & 7;
#pragma unroll
            for (int js = 0; js < 2; js++) {
                int sl = js * 4 + (lane >> 4);
                bf16x8 vh_ = *(const bf16x8*)&Vt[0][rv + ((sl ^ d7) * 8)];
                bf16x8 vl_ = *(const bf16x8*)&Vt[1][rv + ((sl ^ d7) * 8)];
                int po = q_ * 64 + ((sl ^ qx) * 8);
                bf16x8 ph_ = *(const bf16x8*)&Pb[wave][0][po];
                bf16x8 pl_ = *(const bf16x8*)&Pb[wave][1][po];
                oa[dt] = MFMA_BF16(vh_, ph_, oa[dt], 0, 0, 0);
                oa[dt] = MFMA_BF16(vh_, pl_, oa[dt], 0, 0, 0);
                oa[dt] = MFMA_BF16(vl_, ph_, oa[dt], 0, 0, 0);
            }
        }
    }

    float inv = 1.0f / lreg;
#pragma unroll
    for (int dt = 0; dt < 4; dt++) {
        int db = dt * 16 + (lane >> 4) * 4;
        int uo = q_ * 64 + (((db >> 3) ^ qx) * 8) + (db & 7);
        ushort4 wh, wl;
        split2(oa[dt][0] * inv, wh.x, wl.x);
        split2(oa[dt][1] * inv, wh.y, wl.y);
        split2(oa[dt][2] * inv, wh.z, wl.z);
        split2(oa[dt][3] * inv, wh.w, wl.w);
        *(ushort4*)&Pb[wave][0][uo] = wh;
        *(ushort4*)&Pb[wave][1][uo] = wl;
    }
    lds_fence();
#pragma unroll
    for (int pass = 0; pass < 2; pass++) {
        int qq = lane >> 2;
        int sl = (lane & 3) + pass * 4;
        int uo = qq * 64 + ((sl ^ (qq & 7)) * 8);
        bf16x8 vh_ = *(const bf16x8*)&Pb[wave][0][uo];
        bf16x8 vl_ = *(const bf16x8*)&Pb[wave][1][uo];
        size_t orow = (size_t)(b * n + q0 + wave * 16 + qq) * INNER
                    + h * HEAD_DIM + sl * 8;
        *(bf16x8*)&oh[orow] = vh_;
        *(bf16x8*)&ol[orow] = vl_;
    }
}

// ---------------------------------------------------------------------------
// Host launch
// ---------------------------------------------------------------------------
extern "C" void kernel_launch(void* const* d_in, const int* in_sizes, int n_in,
                              void* d_out, int out_size, void* d_ws, size_t ws_size,
                              hipStream_t stream)
{
    const float* x_in   = (const float*)d_in[0];
    const float* Wqkv   = (const float*)d_in[1];
    const float* Wout   = (const float*)d_in[2];
    const float* ln1_s  = (const float*)d_in[3];
    const float* ln1_b  = (const float*)d_in[4];
    const float* W1     = (const float*)d_in[5];
    const float* b1     = (const float*)d_in[6];
    const float* W2     = (const float*)d_in[7];
    const float* b2     = (const float*)d_in[8];
    const float* ln2_s  = (const float*)d_in[9];
    const float* ln2_b  = (const float*)d_in[10];
    const float* lnf_s  = (const float*)d_in[11];
    const float* lnf_b  = (const float*)d_in[12];
    float* outp = (float*)d_out;

    int rows = in_sizes[0] / D_MODEL;   // 4096
    int n = 2048;
    int batch = rows / n;               // 2
    int nbh = batch * N_HEADS;          // 32
    int qblocks = n / 64;               // 32

    // ---- workspace (~134 MB) ----
    char* p = (char*)d_ws;
    float* x = (float*)p;  p += (size_t)rows * D_MODEL * 4;
    u16* hh  = (u16*)p;    p += (size_t)rows * D_MODEL * 2;
    u16* hl  = (u16*)p;    p += (size_t)rows * D_MODEL * 2;
    u16* qkvh = (u16*)p;
    u16* ffh  = (u16*)p;   p += (size_t)rows * FF_DIM * 2;
    u16* qkvl = (u16*)p;
    u16* ffl  = (u16*)p;   p += (size_t)rows * FF_DIM * 2;
    u16* vth = (u16*)p;    p += (size_t)nbh * HEAD_DIM * n * 2;
    u16* vtl = (u16*)p;    p += (size_t)nbh * HEAD_DIM * n * 2;
    u16* wbh = (u16*)p;    p += (size_t)FF_DIM * D_MODEL * 2;
    u16* wbl = (u16*)p;    p += (size_t)FF_DIM * D_MODEL * 2;

    hipMemcpyAsync(x, x_in, (size_t)rows * D_MODEL * 4, hipMemcpyDeviceToDevice, stream);

    dim3 blk(256);
    int ntm = rows / 128;               // 32
    for (int i = 0; i < N_LAYERS; i++) {
        const float* Wqkv_i = Wqkv + (size_t)i * D_MODEL * QKV3;
        const float* Wout_i = Wout + (size_t)i * INNER * D_MODEL;
        const float* W1_i   = W1 + (size_t)i * D_MODEL * FF_DIM;
        const float* W2_i   = W2 + (size_t)i * FF_DIM * D_MODEL;

        // -- attention block --
        wsplit_kernel<<<dim3(QKV3/32, D_MODEL/32), blk, 0, stream>>>(Wqkv_i, wbh, wbl, D_MODEL, QKV3);
        ln_kernel<true><<<rows, blk, 0, stream>>>(x, ln1_s + i*D_MODEL, ln1_b + i*D_MODEL,
                                                  nullptr, hh, hl);
        mfma_gemm<false,false,false,true><<<ntm * (QKV3/128), blk, 0, stream>>>(
            hh, hl, wbh, wbl, nullptr, nullptr, nullptr, qkvh, qkvl, rows, QKV3, D_MODEL, 4);
        vtprep<<<dim3(n/64, nbh), blk, 0, stream>>>(qkvh, qkvl, vth, vtl, n);
        attn_mfma<<<nbh * qblocks, blk, 0, stream>>>(qkvh, qkvl, vth, vtl, hh, hl, n, qblocks);
        wsplit_kernel<<<dim3(D_MODEL/32, INNER/32), blk, 0, stream>>>(Wout_i, wbh, wbl, INNER, D_MODEL);
        mfma_gemm<false,true,false,false><<<ntm * (D_MODEL/128), blk, 0, stream>>>(
            hh, hl, wbh, wbl, nullptr, x, x, nullptr, nullptr, rows, D_MODEL, INNER, 4);

        // -- feedforward block --
        ln_kernel<true><<<rows, blk, 0, stream>>>(x, ln2_s + i*D_MODEL, ln2_b + i*D_MODEL,
                                                  nullptr, hh, hl);
        wsplit_kernel<<<dim3(FF_DIM/32, D_MODEL/32), blk, 0, stream>>>(W1_i, wbh, wbl, D_MODEL, FF_DIM);
        mfma_gemm<true,false,true,true><<<ntm * (FF_DIM/128), blk, 0, stream>>>(
            hh, hl, wbh, wbl, b1 + (size_t)i*FF_DIM, nullptr, nullptr, ffh, ffl,
            rows, FF_DIM, D_MODEL, 4);
        wsplit_kernel<<<dim3(D_MODEL/32, FF_DIM/32), blk, 0, stream>>>(W2_i, wbh, wbl, FF_DIM, D_MODEL);
        mfma_gemm<true,true,false,false><<<ntm * (D_MODEL/128), blk, 0, stream>>>(
            ffh, ffl, wbh, wbl, b2 + (size_t)i*D_MODEL, x, x, nullptr, nullptr,
            rows, D_MODEL, FF_DIM, 2);
    }
    ln_kernel<false><<<rows, blk, 0, stream>>>(x, lnf_s, lnf_b, outp, nullptr, nullptr);
}